// Round 1
// baseline (701.987 us; speedup 1.0000x reference)
//
#include <hip/hip_runtime.h>
#include <math.h>

#define S 128
#define L (S*S)            // 16384
#define AK 25
#define KA (AK*AK)         // 625
#define LK 49
#define KL (LK*LK)         // 2401
#define XW 152             // S + AK - 1
#define PI2 1.57079632679489662f

// ws layout (float offsets)
#define WS_AFFENV 0
#define WS_SRE    1024
#define WS_LRIENV 2048
#define WS_AFF    8192
#define WS_WSUM   24576
#define WS_LAT    40960
#define WS_LATS   57344
#define WS_LM     73728
#define WS_PART   90112
// total ~94208 floats (~368 KB)

// out layout (float offsets): raw_aff[16384], lat[16384], corr[1], x_tiles[10240000]
#define OUT_LAT   16384
#define OUT_CORR  32768
#define OUT_XT    32769

__global__ __launch_bounds__(256) void init_consts(float* __restrict__ ws) {
    const int t = threadIdx.x;
    float* affenv = ws + WS_AFFENV;
    float* sre    = ws + WS_SRE;
    float* lri    = ws + WS_LRIENV;
    __shared__ float red[256];

    // AFF_ENV: rcos(25,25)^2 * circle(25,12.5); max==1 at center
    for (int k = t; k < KA; k += 256) {
        int ky = k / AK, kx = k - ky * AK;
        float dy = (float)ky - 12.0f, dx = (float)kx - 12.0f;
        float rd = sqrtf(dx*dx + dy*dy);
        float c  = cosf(fminf(rd * (1.0f/25.0f), 1.0f) * PI2);
        affenv[k] = c*c * (rd < 12.5f ? 1.0f : 0.0f);
    }

    // SRE: rcos(5,5)^2 * circle(5,2.5), normalized to sum 1
    float myv = 0.0f;
    if (t < 25) {
        int ky = t / 5, kx = t - ky * 5;
        float dy = (float)ky - 2.0f, dx = (float)kx - 2.0f;
        float rd = sqrtf(dx*dx + dy*dy);
        float c  = cosf(fminf(rd * 0.2f, 1.0f) * PI2);
        myv = c*c * (rd < 2.5f ? 1.0f : 0.0f);
    }
    red[t] = myv;
    __syncthreads();
    for (int off = 128; off > 0; off >>= 1) {
        if (t < off) red[t] += red[t + off];
        __syncthreads();
    }
    float ssum = red[0];
    __syncthreads();
    if (t < 25) sre[t] = myv / ssum;

    // LRI_ENV: rcos(49,49)^2 * circle(49,24.5) * (1 - rcos(49,5)^2*circle(49,2.5)), / max
    float localmax = 0.0f;
    for (int k = t; k < KL; k += 256) {
        int ky = k / LK, kx = k - ky * LK;
        float dy = (float)ky - 24.0f, dx = (float)kx - 24.0f;
        float rd = sqrtf(dx*dx + dy*dy);
        float ci = cosf(fminf(rd * 0.2f, 1.0f) * PI2);
        float im = ci*ci * (rd < 2.5f ? 1.0f : 0.0f);
        float co = cosf(fminf(rd * (1.0f/49.0f), 1.0f) * PI2);
        float le = co*co * (rd < 24.5f ? 1.0f : 0.0f) * (1.0f - im);
        lri[k] = le;
        localmax = fmaxf(localmax, le);
    }
    red[t] = localmax;
    __syncthreads();
    for (int off = 128; off > 0; off >>= 1) {
        if (t < off) red[t] = fmaxf(red[t], red[t + off]);
        __syncthreads();
    }
    float m = red[0];
    __syncthreads();
    float invm = 1.0f / m;
    for (int k = t; k < KL; k += 256) lri[k] *= invm;
}

// Afferent: wave per unit; writes x_tiles + raw_aff, stores aff (=dot/rsum - ada) to ws
__global__ __launch_bounds__(256) void aff_kernel(
    const float* __restrict__ x, const float* __restrict__ rfs,
    const float* __restrict__ ada, const float* __restrict__ affenv,
    float* __restrict__ raw_aff_out, float* __restrict__ xtiles_out,
    float* __restrict__ aff_ws)
{
    const int wave = threadIdx.x >> 6, lane = threadIdx.x & 63;
    const int unit = blockIdx.x * 4 + wave;
    const int r = unit >> 7, c = unit & 127;
    const float* wrow = rfs + (size_t)unit * KA;
    float* trow = xtiles_out + (size_t)unit * KA;
    float adot = 0.0f, rsum = 0.0f;
    for (int k = lane; k < KA; k += 64) {
        int ky = (int)(((unsigned)k * 83887u) >> 21);   // k/25 for k<625
        int kx = k - ky * 25;
        float xv = x[(r + ky) * XW + (c + kx)];
        float xt = xv * affenv[k];
        trow[k] = xt;
        float w = wrow[k];
        adot = fmaf(xt, w, adot);
        rsum += w;
    }
    for (int off = 32; off > 0; off >>= 1) {
        adot += __shfl_down(adot, off);
        rsum += __shfl_down(rsum, off);
    }
    if (lane == 0) {
        float inv = 1.0f / rsum;
        raw_aff_out[unit] = 62.5f * adot * inv;
        aff_ws[unit] = adot * inv - ada[unit];
    }
}

// 5x5 reflect-pad smoothing conv
__global__ __launch_bounds__(256) void smooth_kernel(
    const float* __restrict__ lat, const float* __restrict__ sre,
    float* __restrict__ lat_s)
{
    const int idx = blockIdx.x * 256 + threadIdx.x;
    const int r = idx >> 7, c = idx & 127;
    float acc = 0.0f;
    #pragma unroll
    for (int a = 0; a < 5; a++) {
        int rr = r + a - 2;
        rr = rr < 0 ? -rr : (rr > 127 ? 254 - rr : rr);
        #pragma unroll
        for (int b = 0; b < 5; b++) {
            int cc = c + b - 2;
            cc = cc < 0 ? -cc : (cc > 127 ? 254 - cc : cc);
            acc = fmaf(sre[a * 5 + b], lat[rr * 128 + cc], acc);
        }
    }
    lat_s[idx] = acc;
}

// Lateral inhibition + state update. Wave per unit, 4 units/block, LDS window of lat_s.
__global__ __launch_bounds__(256) void lat_kernel(
    const float* __restrict__ lw, const float* __restrict__ lat_s,
    const float* __restrict__ aff, const float* __restrict__ lri,
    float* __restrict__ wsum_ws, const float* __restrict__ lm_in,
    float* __restrict__ lm_out, float* __restrict__ lat_out,
    float* __restrict__ lat_final, int first_iter)
{
    __shared__ float win[49 * 52];
    const int tid = threadIdx.x;
    const int wave = tid >> 6, lane = tid & 63;
    const int unit0 = blockIdx.x * 4;
    const int r = unit0 >> 7, c0 = unit0 & 127;

    for (int i = tid; i < 49 * 52; i += 256) {
        int wy = i / 52, wx = i - wy * 52;
        int rr = r - 24 + wy, cc = c0 - 24 + wx;
        float v = 0.0f;
        if (rr >= 0 && rr < 128 && cc >= 0 && cc < 128) v = lat_s[rr * 128 + cc];
        win[i] = v;
    }
    __syncthreads();

    const int unit = unit0 + wave;
    const float* wrow = lw + (size_t)unit * KL;
    float dot = 0.0f, wsum = 0.0f;
    if (first_iter) {
        for (int k = lane; k < KL; k += 64) {
            float w = wrow[k];
            int ky = (int)(((unsigned)k * 42800u) >> 21);   // k/49 for k<2401
            int kx = k - ky * 49;
            float t = win[ky * 52 + kx + wave];
            dot = fmaf(w, t * lri[k], dot);
            wsum += w;
        }
    } else {
        for (int k = lane; k < KL; k += 64) {
            float w = wrow[k];
            int ky = (int)(((unsigned)k * 42800u) >> 21);
            int kx = k - ky * 49;
            float t = win[ky * 52 + kx + wave];
            dot = fmaf(w, t * lri[k], dot);
        }
    }
    for (int off = 32; off > 0; off >>= 1) {
        dot += __shfl_down(dot, off);
        wsum += __shfl_down(wsum, off);
    }
    if (lane == 0) {
        if (first_iter) wsum_ws[unit] = wsum;
        else wsum = wsum_ws[unit];
        float lat_neg = dot / wsum;
        float ls = win[24 * 52 + 24 + wave];
        float ln = fmaxf(ls + aff[unit] - 2.5f * lat_neg, 0.0f) * 2.2f;
        ln = tanhf(ln * 1.5f) * (1.0f / 1.5f);
        float lm = 0.5f * lm_in[unit] + 0.5f * ln;
        lm_out[unit] = lm;
        lat_out[unit] = ln;
        if (lat_final) lat_final[unit] = ln;
    }
}

// Hebbian: per-unit dot of unfolded lat_mean * LRI_ENV with lat_n; block partial sums
__global__ __launch_bounds__(256) void hebb_kernel(
    const float* __restrict__ lw, const float* __restrict__ lm,
    const float* __restrict__ lri, const float* __restrict__ wsum_ws,
    float* __restrict__ partials)
{
    __shared__ float win[49 * 52];
    __shared__ float wred[4];
    const int tid = threadIdx.x;
    const int wave = tid >> 6, lane = tid & 63;
    const int unit0 = blockIdx.x * 4;
    const int r = unit0 >> 7, c0 = unit0 & 127;

    for (int i = tid; i < 49 * 52; i += 256) {
        int wy = i / 52, wx = i - wy * 52;
        int rr = r - 24 + wy, cc = c0 - 24 + wx;
        float v = 0.0f;
        if (rr >= 0 && rr < 128 && cc >= 0 && cc < 128) v = lm[rr * 128 + cc];
        win[i] = v;
    }
    __syncthreads();

    const int unit = unit0 + wave;
    const float* wrow = lw + (size_t)unit * KL;
    float dot = 0.0f;
    for (int k = lane; k < KL; k += 64) {
        float w = wrow[k];
        int ky = (int)(((unsigned)k * 42800u) >> 21);
        int kx = k - ky * 49;
        float t = win[ky * 52 + kx + wave];
        dot = fmaf(w, t * lri[k], dot);
    }
    for (int off = 32; off > 0; off >>= 1) dot += __shfl_down(dot, off);
    if (lane == 0) {
        float center = win[24 * 52 + 24 + wave];
        wred[wave] = center * (240.1f / wsum_ws[unit]) * dot;
    }
    __syncthreads();
    if (tid == 0) partials[blockIdx.x] = wred[0] + wred[1] + wred[2] + wred[3];
}

__global__ __launch_bounds__(256) void reduce_kernel(
    const float* __restrict__ partials, float* __restrict__ out)
{
    __shared__ float red[256];
    float s = 0.0f;
    for (int i = threadIdx.x; i < 4096; i += 256) s += partials[i];
    red[threadIdx.x] = s;
    __syncthreads();
    for (int off = 128; off > 0; off >>= 1) {
        if (threadIdx.x < off) red[threadIdx.x] += red[threadIdx.x + off];
        __syncthreads();
    }
    if (threadIdx.x == 0) out[0] = red[0];
}

extern "C" void kernel_launch(void* const* d_in, const int* in_sizes, int n_in,
                              void* d_out, int out_size, void* d_ws, size_t ws_size,
                              hipStream_t stream) {
    const float* x        = (const float*)d_in[0];
    const float* rfs      = (const float*)d_in[1];
    const float* lw       = (const float*)d_in[2];
    const float* ada      = (const float*)d_in[3];
    const float* last_lat = (const float*)d_in[4];
    const float* lm0      = (const float*)d_in[5];
    float* out = (float*)d_out;
    float* ws  = (float*)d_ws;

    init_consts<<<1, 256, 0, stream>>>(ws);
    aff_kernel<<<L / 4, 256, 0, stream>>>(x, rfs, ada, ws + WS_AFFENV,
                                          out, out + OUT_XT, ws + WS_AFF);
    for (int it = 0; it < 10; ++it) {
        const float* lat_in = (it == 0) ? last_lat : (ws + WS_LAT);
        const float* lmsrc  = (it == 0) ? lm0 : (ws + WS_LM);
        smooth_kernel<<<L / 256, 256, 0, stream>>>(lat_in, ws + WS_SRE, ws + WS_LATS);
        lat_kernel<<<L / 4, 256, 0, stream>>>(lw, ws + WS_LATS, ws + WS_AFF,
                                              ws + WS_LRIENV, ws + WS_WSUM,
                                              lmsrc, ws + WS_LM, ws + WS_LAT,
                                              (it == 9) ? (out + OUT_LAT) : nullptr,
                                              (it == 0) ? 1 : 0);
    }
    hebb_kernel<<<L / 4, 256, 0, stream>>>(lw, ws + WS_LM, ws + WS_LRIENV,
                                           ws + WS_WSUM, ws + WS_PART);
    reduce_kernel<<<1, 256, 0, stream>>>(ws + WS_PART, out + OUT_CORR);
}

// Round 2
// 652.600 us; speedup vs baseline: 1.0757x; 1.0757x over previous
//
#include <hip/hip_runtime.h>
#include <math.h>

#define S 128
#define L (S*S)            // 16384
#define AK 25
#define KA (AK*AK)         // 625
#define LK 49
#define KL (LK*LK)         // 2401
#define XW 152             // S + AK - 1
#define PI2 1.57079632679489662f

// ws layout (float offsets)
#define WS_AFFENV  0
#define WS_SRE     1024
#define WS_LRIRAW  2048
#define WS_LRID    5120     // deinterleaved lri, 2404 floats
#define WS_AFF     8192
#define WS_WSUM    24576
#define WS_LAT     40960
#define WS_LATS    57344
#define WS_LM      73728
#define WS_PART    90112

// out layout (float offsets): raw_aff[16384], lat[16384], corr[1], x_tiles[10240000]
#define OUT_LAT   16384
#define OUT_CORR  32768
#define OUT_XT    32769

__global__ __launch_bounds__(256) void init_consts(float* __restrict__ ws) {
    const int t = threadIdx.x;
    float* affenv = ws + WS_AFFENV;
    float* sre    = ws + WS_SRE;
    float* lrraw  = ws + WS_LRIRAW;
    float* lrid   = ws + WS_LRID;
    __shared__ float red[256];

    // AFF_ENV: rcos(25,25)^2 * circle(25,12.5); max==1 at center
    for (int k = t; k < KA; k += 256) {
        int ky = k / AK, kx = k - ky * AK;
        float dy = (float)ky - 12.0f, dx = (float)kx - 12.0f;
        float rd = sqrtf(dx*dx + dy*dy);
        float c  = cosf(fminf(rd * (1.0f/25.0f), 1.0f) * PI2);
        affenv[k] = c*c * (rd < 12.5f ? 1.0f : 0.0f);
    }

    // SRE: rcos(5,5)^2 * circle(5,2.5), normalized to sum 1
    float myv = 0.0f;
    if (t < 25) {
        int ky = t / 5, kx = t - ky * 5;
        float dy = (float)ky - 2.0f, dx = (float)kx - 2.0f;
        float rd = sqrtf(dx*dx + dy*dy);
        float c  = cosf(fminf(rd * 0.2f, 1.0f) * PI2);
        myv = c*c * (rd < 2.5f ? 1.0f : 0.0f);
    }
    red[t] = myv;
    __syncthreads();
    for (int off = 128; off > 0; off >>= 1) {
        if (t < off) red[t] += red[t + off];
        __syncthreads();
    }
    float ssum = red[0];
    __syncthreads();
    if (t < 25) sre[t] = myv / ssum;

    // LRI_ENV raw + max
    float localmax = 0.0f;
    for (int k = t; k < KL; k += 256) {
        int ky = k / LK, kx = k - ky * LK;
        float dy = (float)ky - 24.0f, dx = (float)kx - 24.0f;
        float rd = sqrtf(dx*dx + dy*dy);
        float ci = cosf(fminf(rd * 0.2f, 1.0f) * PI2);
        float im = ci*ci * (rd < 2.5f ? 1.0f : 0.0f);
        float co = cosf(fminf(rd * (1.0f/49.0f), 1.0f) * PI2);
        float le = co*co * (rd < 24.5f ? 1.0f : 0.0f) * (1.0f - im);
        lrraw[k] = le;
        localmax = fmaxf(localmax, le);
    }
    red[t] = localmax;
    __syncthreads();
    for (int off = 128; off > 0; off >>= 1) {
        if (t < off) red[t] = fmaxf(red[t], red[t + off]);
        __syncthreads();
    }
    float invm = 1.0f / red[0];
    __syncthreads();
    // deinterleaved: lrid[(k&3)*601 + (k>>2)] = lri[k]
    for (int k = t; k < KL; k += 256)
        lrid[(k & 3) * 601 + (k >> 2)] = lrraw[k] * invm;
}

// Afferent: wave per unit; writes x_tiles + raw_aff, stores aff (=dot/rsum - ada) to ws
__global__ __launch_bounds__(256) void aff_kernel(
    const float* __restrict__ x, const float* __restrict__ rfs,
    const float* __restrict__ ada, const float* __restrict__ affenv,
    float* __restrict__ raw_aff_out, float* __restrict__ xtiles_out,
    float* __restrict__ aff_ws)
{
    const int wave = threadIdx.x >> 6, lane = threadIdx.x & 63;
    const int unit = blockIdx.x * 4 + wave;
    const int r = unit >> 7, c = unit & 127;
    const float* wrow = rfs + (size_t)unit * KA;
    float* trow = xtiles_out + (size_t)unit * KA;
    float adot = 0.0f, rsum = 0.0f;
    for (int k = lane; k < KA; k += 64) {
        int ky = (int)(((unsigned)k * 83887u) >> 21);   // k/25 for k<625
        int kx = k - ky * 25;
        float xv = x[(r + ky) * XW + (c + kx)];
        float xt = xv * affenv[k];
        trow[k] = xt;
        float w = wrow[k];
        adot = fmaf(xt, w, adot);
        rsum += w;
    }
    for (int off = 32; off > 0; off >>= 1) {
        adot += __shfl_down(adot, off);
        rsum += __shfl_down(rsum, off);
    }
    if (lane == 0) {
        float inv = 1.0f / rsum;
        raw_aff_out[unit] = 62.5f * adot * inv;
        aff_ws[unit] = adot * inv - ada[unit];
    }
}

// 5x5 reflect-pad smoothing conv
__global__ __launch_bounds__(256) void smooth_kernel(
    const float* __restrict__ lat, const float* __restrict__ sre,
    float* __restrict__ lat_s)
{
    const int idx = blockIdx.x * 256 + threadIdx.x;
    const int r = idx >> 7, c = idx & 127;
    float acc = 0.0f;
    #pragma unroll
    for (int a = 0; a < 5; a++) {
        int rr = r + a - 2;
        rr = rr < 0 ? -rr : (rr > 127 ? 254 - rr : rr);
        #pragma unroll
        for (int b = 0; b < 5; b++) {
            int cc = c + b - 2;
            cc = cc < 0 ? -cc : (cc > 127 ? 254 - cc : cc);
            acc = fmaf(sre[a * 5 + b], lat[rr * 128 + cc], acc);
        }
    }
    lat_s[idx] = acc;
}

// Lateral inhibition + state update. Wave per unit; aligned float4 weight loads;
// deinterleaved LDS for window and lri (lane k-stride of 4 stays conflict-free).
__global__ __launch_bounds__(256) void lat_kernel(
    const float* __restrict__ lw, const float* __restrict__ lat_s,
    const float* __restrict__ aff, const float* __restrict__ lri_d,
    float* __restrict__ wsum_ws, const float* __restrict__ lm_in,
    float* __restrict__ lm_out, float* __restrict__ lat_out,
    float* __restrict__ lat_final, int first_iter)
{
    __shared__ float win[4 * 637];   // [(r&3)*637 + (r>>2)], r = ky*52 + kx + wave
    __shared__ float lriS[4 * 601];  // [(k&3)*601 + (k>>2)]
    const int tid = threadIdx.x;
    const int wave = tid >> 6, lane = tid & 63;
    const int unit0 = blockIdx.x * 4;
    const int r0 = unit0 >> 7, c0 = unit0 & 127;

    for (int i = tid; i < 2404; i += 256) lriS[i] = lri_d[i];
    for (int i = tid; i < 49 * 52; i += 256) {
        int wy = i / 52, wx = i - wy * 52;
        int rr = r0 - 24 + wy, cc = c0 - 24 + wx;
        float v = 0.0f;
        if (rr >= 0 && rr < 128 && cc >= 0 && cc < 128) v = lat_s[rr * 128 + cc];
        win[(i & 3) * 637 + (i >> 2)] = v;
    }
    __syncthreads();

    const int unit = unit0 + wave;
    const int base = unit * KL;            // dword index
    const int h = (-base) & 3;             // head count; base+h is 16B-aligned
    const int tl = (base + KL) & 3;        // tail count
    const int m4 = (KL - h - tl) >> 2;     // aligned quads

    float dot = 0.0f, wsum = 0.0f;
    if (lane < h) {                        // head: k in [0,h), ky = 0
        float w = lw[base + lane];
        int rr = lane + wave;
        float li = lriS[(lane & 3) * 601 + (lane >> 2)];
        float tv = win[(rr & 3) * 637 + (rr >> 2)];
        dot = fmaf(w * li, tv, dot);
        wsum += w;
    }
    if (lane < tl) {                       // tail
        int k = KL - tl + lane;
        float w = lw[base + k];
        int ky = (int)(((unsigned)k * 42800u) >> 21);  // k/49
        int rr = k + 3 * ky + wave;
        float li = lriS[(k & 3) * 601 + (k >> 2)];
        float tv = win[(rr & 3) * 637 + (rr >> 2)];
        dot = fmaf(w * li, tv, dot);
        wsum += w;
    }
    const float4* lw4 = (const float4*)(lw + base + h);
    for (int q = lane; q < m4; q += 64) {
        float4 w4 = lw4[q];
        int kq = h + (q << 2);
        #pragma unroll
        for (int e = 0; e < 4; ++e) {
            int k = kq + e;
            float w = (e == 0) ? w4.x : (e == 1) ? w4.y : (e == 2) ? w4.z : w4.w;
            int ky = (int)(((unsigned)k * 42800u) >> 21);
            int rr = k + 3 * ky + wave;
            float li = lriS[(k & 3) * 601 + (k >> 2)];
            float tv = win[(rr & 3) * 637 + (rr >> 2)];
            dot = fmaf(w * li, tv, dot);
            wsum += w;
        }
    }
    for (int off = 32; off > 0; off >>= 1) {
        dot += __shfl_down(dot, off);
        wsum += __shfl_down(wsum, off);
    }
    if (lane == 0) {
        if (first_iter) wsum_ws[unit] = wsum;
        else wsum = wsum_ws[unit];
        float lat_neg = dot / wsum;
        int rc = 24 * 52 + 24 + wave;
        float ls = win[(rc & 3) * 637 + (rc >> 2)];
        float ln = fmaxf(ls + aff[unit] - 2.5f * lat_neg, 0.0f) * 2.2f;
        ln = tanhf(ln * 1.5f) * (1.0f / 1.5f);
        float lm = 0.5f * lm_in[unit] + 0.5f * ln;
        lm_out[unit] = lm;
        lat_out[unit] = ln;
        if (lat_final) lat_final[unit] = ln;
    }
}

// Hebbian: same optimized structure over lat_mean; block partial sums
__global__ __launch_bounds__(256) void hebb_kernel(
    const float* __restrict__ lw, const float* __restrict__ lm,
    const float* __restrict__ lri_d, const float* __restrict__ wsum_ws,
    float* __restrict__ partials)
{
    __shared__ float win[4 * 637];
    __shared__ float lriS[4 * 601];
    __shared__ float wred[4];
    const int tid = threadIdx.x;
    const int wave = tid >> 6, lane = tid & 63;
    const int unit0 = blockIdx.x * 4;
    const int r0 = unit0 >> 7, c0 = unit0 & 127;

    for (int i = tid; i < 2404; i += 256) lriS[i] = lri_d[i];
    for (int i = tid; i < 49 * 52; i += 256) {
        int wy = i / 52, wx = i - wy * 52;
        int rr = r0 - 24 + wy, cc = c0 - 24 + wx;
        float v = 0.0f;
        if (rr >= 0 && rr < 128 && cc >= 0 && cc < 128) v = lm[rr * 128 + cc];
        win[(i & 3) * 637 + (i >> 2)] = v;
    }
    __syncthreads();

    const int unit = unit0 + wave;
    const int base = unit * KL;
    const int h = (-base) & 3;
    const int tl = (base + KL) & 3;
    const int m4 = (KL - h - tl) >> 2;

    float dot = 0.0f;
    if (lane < h) {
        float w = lw[base + lane];
        int rr = lane + wave;
        dot = fmaf(w * lriS[(lane & 3) * 601 + (lane >> 2)],
                   win[(rr & 3) * 637 + (rr >> 2)], dot);
    }
    if (lane < tl) {
        int k = KL - tl + lane;
        float w = lw[base + k];
        int ky = (int)(((unsigned)k * 42800u) >> 21);
        int rr = k + 3 * ky + wave;
        dot = fmaf(w * lriS[(k & 3) * 601 + (k >> 2)],
                   win[(rr & 3) * 637 + (rr >> 2)], dot);
    }
    const float4* lw4 = (const float4*)(lw + base + h);
    for (int q = lane; q < m4; q += 64) {
        float4 w4 = lw4[q];
        int kq = h + (q << 2);
        #pragma unroll
        for (int e = 0; e < 4; ++e) {
            int k = kq + e;
            float w = (e == 0) ? w4.x : (e == 1) ? w4.y : (e == 2) ? w4.z : w4.w;
            int ky = (int)(((unsigned)k * 42800u) >> 21);
            int rr = k + 3 * ky + wave;
            dot = fmaf(w * lriS[(k & 3) * 601 + (k >> 2)],
                       win[(rr & 3) * 637 + (rr >> 2)], dot);
        }
    }
    for (int off = 32; off > 0; off >>= 1) dot += __shfl_down(dot, off);
    if (lane == 0) {
        int rc = 24 * 52 + 24 + wave;
        float center = win[(rc & 3) * 637 + (rc >> 2)];
        wred[wave] = center * (240.1f / wsum_ws[unit]) * dot;
    }
    __syncthreads();
    if (tid == 0) partials[blockIdx.x] = wred[0] + wred[1] + wred[2] + wred[3];
}

__global__ __launch_bounds__(256) void reduce_kernel(
    const float* __restrict__ partials, float* __restrict__ out)
{
    __shared__ float red[256];
    float s = 0.0f;
    for (int i = threadIdx.x; i < 4096; i += 256) s += partials[i];
    red[threadIdx.x] = s;
    __syncthreads();
    for (int off = 128; off > 0; off >>= 1) {
        if (threadIdx.x < off) red[threadIdx.x] += red[threadIdx.x + off];
        __syncthreads();
    }
    if (threadIdx.x == 0) out[0] = red[0];
}

extern "C" void kernel_launch(void* const* d_in, const int* in_sizes, int n_in,
                              void* d_out, int out_size, void* d_ws, size_t ws_size,
                              hipStream_t stream) {
    const float* x        = (const float*)d_in[0];
    const float* rfs      = (const float*)d_in[1];
    const float* lw       = (const float*)d_in[2];
    const float* ada      = (const float*)d_in[3];
    const float* last_lat = (const float*)d_in[4];
    const float* lm0      = (const float*)d_in[5];
    float* out = (float*)d_out;
    float* ws  = (float*)d_ws;

    init_consts<<<1, 256, 0, stream>>>(ws);
    aff_kernel<<<L / 4, 256, 0, stream>>>(x, rfs, ada, ws + WS_AFFENV,
                                          out, out + OUT_XT, ws + WS_AFF);
    for (int it = 0; it < 10; ++it) {
        const float* lat_in = (it == 0) ? last_lat : (ws + WS_LAT);
        const float* lmsrc  = (it == 0) ? lm0 : (ws + WS_LM);
        smooth_kernel<<<L / 256, 256, 0, stream>>>(lat_in, ws + WS_SRE, ws + WS_LATS);
        lat_kernel<<<L / 4, 256, 0, stream>>>(lw, ws + WS_LATS, ws + WS_AFF,
                                              ws + WS_LRID, ws + WS_WSUM,
                                              lmsrc, ws + WS_LM, ws + WS_LAT,
                                              (it == 9) ? (out + OUT_LAT) : nullptr,
                                              (it == 0) ? 1 : 0);
    }
    hebb_kernel<<<L / 4, 256, 0, stream>>>(lw, ws + WS_LM, ws + WS_LRID,
                                           ws + WS_WSUM, ws + WS_PART);
    reduce_kernel<<<1, 256, 0, stream>>>(ws + WS_PART, out + OUT_CORR);
}

// Round 4
// 638.137 us; speedup vs baseline: 1.1001x; 1.0227x over previous
//
#include <hip/hip_runtime.h>
#include <math.h>

#define S 128
#define L (S*S)            // 16384
#define AK 25
#define KA 625
#define LK 49
#define KL 2401
#define XW 152
#define PI2 1.57079632679489662f

typedef float v4f __attribute__((ext_vector_type(4)));

// ws layout (float offsets)
#define WS_AENVD   0        // deinterleaved aff env, 628 floats
#define WS_SRE     1024
#define WS_LRIRAW  2048
#define WS_LRID    5120     // deinterleaved lri, 2404 floats
#define WS_AFF     8192
#define WS_WSUM    24576
#define WS_LAT     40960
#define WS_LATS    57344
#define WS_LM      73728
#define WS_PART    90112

// out layout (float offsets): raw_aff[16384], lat[16384], corr[1], x_tiles[10240000]
#define OUT_LAT   16384
#define OUT_CORR  32768
#define OUT_XT    32769

__global__ __launch_bounds__(256) void init_consts(float* __restrict__ ws) {
    const int t = threadIdx.x;
    float* aenvd  = ws + WS_AENVD;
    float* sre    = ws + WS_SRE;
    float* lrraw  = ws + WS_LRIRAW;
    float* lrid   = ws + WS_LRID;
    __shared__ float red[256];

    // AFF_ENV: rcos(25,25)^2 * circle(25,12.5); max==1 at center; deinterleaved
    for (int k = t; k < KA; k += 256) {
        int ky = k / AK, kx = k - ky * AK;
        float dy = (float)ky - 12.0f, dx = (float)kx - 12.0f;
        float rd = sqrtf(dx*dx + dy*dy);
        float c  = cosf(fminf(rd * (1.0f/25.0f), 1.0f) * PI2);
        aenvd[(k & 3) * 157 + (k >> 2)] = c*c * (rd < 12.5f ? 1.0f : 0.0f);
    }

    // SRE: rcos(5,5)^2 * circle(5,2.5), normalized to sum 1
    float myv = 0.0f;
    if (t < 25) {
        int ky = t / 5, kx = t - ky * 5;
        float dy = (float)ky - 2.0f, dx = (float)kx - 2.0f;
        float rd = sqrtf(dx*dx + dy*dy);
        float c  = cosf(fminf(rd * 0.2f, 1.0f) * PI2);
        myv = c*c * (rd < 2.5f ? 1.0f : 0.0f);
    }
    red[t] = myv;
    __syncthreads();
    for (int off = 128; off > 0; off >>= 1) {
        if (t < off) red[t] += red[t + off];
        __syncthreads();
    }
    float ssum = red[0];
    __syncthreads();
    if (t < 25) sre[t] = myv / ssum;

    // LRI_ENV raw + max
    float localmax = 0.0f;
    for (int k = t; k < KL; k += 256) {
        int ky = k / LK, kx = k - ky * LK;
        float dy = (float)ky - 24.0f, dx = (float)kx - 24.0f;
        float rd = sqrtf(dx*dx + dy*dy);
        float ci = cosf(fminf(rd * 0.2f, 1.0f) * PI2);
        float im = ci*ci * (rd < 2.5f ? 1.0f : 0.0f);
        float co = cosf(fminf(rd * (1.0f/49.0f), 1.0f) * PI2);
        float le = co*co * (rd < 24.5f ? 1.0f : 0.0f) * (1.0f - im);
        lrraw[k] = le;
        localmax = fmaxf(localmax, le);
    }
    red[t] = localmax;
    __syncthreads();
    for (int off = 128; off > 0; off >>= 1) {
        if (t < off) red[t] = fmaxf(red[t], red[t + off]);
        __syncthreads();
    }
    float invm = 1.0f / red[0];
    __syncthreads();
    for (int k = t; k < KL; k += 256)
        lrid[(k & 3) * 601 + (k >> 2)] = lrraw[k] * invm;
}

// Afferent: wave per unit; staged register loads; LDS x-window + env; v4f nt stores
__global__ __launch_bounds__(256) void aff_kernel(
    const float* __restrict__ x, const float* __restrict__ rfs,
    const float* __restrict__ ada, const float* __restrict__ aenv_d,
    float* __restrict__ raw_aff_out, float* __restrict__ xtiles_out,
    float* __restrict__ aff_ws)
{
    __shared__ float xwin[700];   // [(j&3)*175 + (j>>2)], j = ky*28 + kx + wave
    __shared__ float env[628];    // [(k&3)*157 + (k>>2)]
    const int tid = threadIdx.x;
    const int wave = tid >> 6, lane = tid & 63;
    const int unit0 = blockIdx.x * 4;
    const int r0 = unit0 >> 7, c0 = unit0 & 127;

    for (int i = tid; i < 628; i += 256) env[i] = aenv_d[i];
    for (int i = tid; i < 700; i += 256) {
        int wy = i / 28, wx = i - wy * 28;
        xwin[(i & 3) * 175 + (i >> 2)] = x[(r0 + wy) * XW + c0 + wx];
    }
    __syncthreads();

    const int unit = unit0 + wave;
    const int base = unit * KA;
    const int h = (-base) & 3;
    const int tl = (base + KA) & 3;
    const int m4 = (KA - h - tl) >> 2;   // 155 or 156
    const int rem = m4 - 128;            // 27 or 28

    const v4f* w4p = (const v4f*)(rfs + base + h);
    v4f wv0 = w4p[lane];
    v4f wv1 = w4p[lane + 64];
    v4f wv2 = (v4f)(0.0f);
    bool has2 = lane < rem;
    if (has2) wv2 = w4p[128 + lane];
    float wh = 0.0f, wt = 0.0f;
    if (lane < h)  wh = rfs[base + lane];
    if (lane < tl) wt = rfs[base + KA - tl + lane];

    float* trow = xtiles_out + (size_t)unit * KA;
    v4f* t4p = (v4f*)(trow + h);
    float adot = 0.0f, rsum = 0.0f;

    if (lane < h) {                       // head: k=lane<3, ky=0
        int j = lane + wave;
        float xt = xwin[(j & 3) * 175 + (j >> 2)] * env[(lane & 3) * 157 + (lane >> 2)];
        trow[lane] = xt;
        adot = fmaf(xt, wh, adot); rsum += wh;
    }
    if (lane < tl) {                      // tail
        int k = KA - tl + lane;
        int ky = (int)(((unsigned)k * 83887u) >> 21);
        int j = k + 3 * ky + wave;
        float xt = xwin[(j & 3) * 175 + (j >> 2)] * env[(k & 3) * 157 + (k >> 2)];
        trow[k] = xt;
        adot = fmaf(xt, wt, adot); rsum += wt;
    }
    #pragma unroll
    for (int i = 0; i < 2; i++) {
        v4f wq = (i == 0) ? wv0 : wv1;
        int q = lane + (i << 6);
        int kq = h + (q << 2);
        v4f st;
        #pragma unroll
        for (int e = 0; e < 4; e++) {
            int k = kq + e;
            int ky = (int)(((unsigned)k * 83887u) >> 21);
            int j = k + 3 * ky + wave;
            float xt = xwin[(j & 3) * 175 + (j >> 2)] * env[(k & 3) * 157 + (k >> 2)];
            st[e] = xt;
            adot = fmaf(xt, wq[e], adot);
            rsum += wq[e];
        }
        __builtin_nontemporal_store(st, &t4p[q]);
    }
    if (has2) {
        int q = 128 + lane;
        int kq = h + (q << 2);
        v4f st;
        #pragma unroll
        for (int e = 0; e < 4; e++) {
            int k = kq + e;
            int ky = (int)(((unsigned)k * 83887u) >> 21);
            int j = k + 3 * ky + wave;
            float xt = xwin[(j & 3) * 175 + (j >> 2)] * env[(k & 3) * 157 + (k >> 2)];
            st[e] = xt;
            adot = fmaf(xt, wv2[e], adot);
            rsum += wv2[e];
        }
        __builtin_nontemporal_store(st, &t4p[q]);
    }

    for (int off = 32; off > 0; off >>= 1) {
        adot += __shfl_down(adot, off);
        rsum += __shfl_down(rsum, off);
    }
    if (lane == 0) {
        float inv = 1.0f / rsum;
        raw_aff_out[unit] = 62.5f * adot * inv;
        aff_ws[unit] = adot * inv - ada[unit];
    }
}

// 5x5 reflect-pad smoothing conv
__global__ __launch_bounds__(256) void smooth_kernel(
    const float* __restrict__ lat, const float* __restrict__ sre,
    float* __restrict__ lat_s)
{
    const int idx = blockIdx.x * 256 + threadIdx.x;
    const int r = idx >> 7, c = idx & 127;
    float acc = 0.0f;
    #pragma unroll
    for (int a = 0; a < 5; a++) {
        int rr = r + a - 2;
        rr = rr < 0 ? -rr : (rr > 127 ? 254 - rr : rr);
        #pragma unroll
        for (int b = 0; b < 5; b++) {
            int cc = c + b - 2;
            cc = cc < 0 ? -cc : (cc > 127 ? 254 - cc : cc);
            acc = fmaf(sre[a * 5 + b], lat[rr * 128 + cc], acc);
        }
    }
    lat_s[idx] = acc;
}

// Lateral inhibition + state update. Wave per unit; all weight loads staged to
// registers up-front (9 unconditional + 1 predicated quads + head/tail).
__global__ __launch_bounds__(256) void lat_kernel(
    const float* __restrict__ lw, const float* __restrict__ lat_s,
    const float* __restrict__ aff, const float* __restrict__ lri_d,
    float* __restrict__ wsum_ws, const float* __restrict__ lm_in,
    float* __restrict__ lm_out, float* __restrict__ lat_out,
    float* __restrict__ lat_final, int first_iter)
{
    __shared__ float win[2548];   // [(rr&3)*637 + (rr>>2)], rr = k + 3*ky + wave
    __shared__ float lriS[2404];  // [(k&3)*601 + (k>>2)]
    const int tid = threadIdx.x;
    const int wave = tid >> 6, lane = tid & 63;
    const int unit0 = blockIdx.x * 4;
    const int r0 = unit0 >> 7, c0 = unit0 & 127;

    for (int i = tid; i < 2404; i += 256) lriS[i] = lri_d[i];
    for (int i = tid; i < 2548; i += 256) {
        int wy = i / 52, wx = i - wy * 52;
        int rr = r0 - 24 + wy, cc = c0 - 24 + wx;
        float v = 0.0f;
        if (rr >= 0 && rr < 128 && cc >= 0 && cc < 128) v = lat_s[rr * 128 + cc];
        win[(i & 3) * 637 + (i >> 2)] = v;
    }
    __syncthreads();

    const int unit = unit0 + wave;
    const int base = unit * KL;
    const int h = (-base) & 3;
    const int tl = (base + KL) & 3;
    const int m4 = (KL - h - tl) >> 2;   // 599 or 600
    const int rem = m4 - 576;            // 23 or 24

    const v4f* w4p = (const v4f*)(lw + base + h);
    v4f wv[9];
    #pragma unroll
    for (int i = 0; i < 9; i++) wv[i] = w4p[lane + (i << 6)];
    v4f wv9 = (v4f)(0.0f);
    bool has9 = lane < rem;
    if (has9) wv9 = w4p[576 + lane];
    float whd = 0.0f, wtl = 0.0f;
    if (lane < h)  whd = lw[base + lane];
    if (lane < tl) wtl = lw[base + KL - tl + lane];

    float dot = 0.0f, wsum = 0.0f;
    if (lane < h) {                       // k=lane<3, ky=0
        int rr = lane + wave;
        dot = fmaf(whd * lriS[(lane & 3) * 601 + (lane >> 2)],
                   win[(rr & 3) * 637 + (rr >> 2)], dot);
        wsum += whd;
    }
    if (lane < tl) {
        int k = KL - tl + lane;
        int ky = (int)(((unsigned)k * 42800u) >> 21);
        int rr = k + 3 * ky + wave;
        dot = fmaf(wtl * lriS[(k & 3) * 601 + (k >> 2)],
                   win[(rr & 3) * 637 + (rr >> 2)], dot);
        wsum += wtl;
    }
    #pragma unroll
    for (int i = 0; i < 9; i++) {
        int kq = h + ((lane + (i << 6)) << 2);
        #pragma unroll
        for (int e = 0; e < 4; e++) {
            int k = kq + e;
            float w = wv[i][e];
            int ky = (int)(((unsigned)k * 42800u) >> 21);
            int rr = k + 3 * ky + wave;
            dot = fmaf(w * lriS[(k & 3) * 601 + (k >> 2)],
                       win[(rr & 3) * 637 + (rr >> 2)], dot);
            wsum += w;
        }
    }
    if (has9) {
        int kq = h + ((576 + lane) << 2);
        #pragma unroll
        for (int e = 0; e < 4; e++) {
            int k = kq + e;
            float w = wv9[e];
            int ky = (int)(((unsigned)k * 42800u) >> 21);
            int rr = k + 3 * ky + wave;
            dot = fmaf(w * lriS[(k & 3) * 601 + (k >> 2)],
                       win[(rr & 3) * 637 + (rr >> 2)], dot);
            wsum += w;
        }
    }

    for (int off = 32; off > 0; off >>= 1) {
        dot += __shfl_down(dot, off);
        wsum += __shfl_down(wsum, off);
    }
    if (lane == 0) {
        if (first_iter) wsum_ws[unit] = wsum;
        else wsum = wsum_ws[unit];
        float lat_neg = dot / wsum;
        int rc = 24 * 52 + 24 + wave;
        float ls = win[(rc & 3) * 637 + (rc >> 2)];
        float ln = fmaxf(ls + aff[unit] - 2.5f * lat_neg, 0.0f) * 2.2f;
        ln = tanhf(ln * 1.5f) * (1.0f / 1.5f);
        float lm = 0.5f * lm_in[unit] + 0.5f * ln;
        lm_out[unit] = lm;
        lat_out[unit] = ln;
        if (lat_final) lat_final[unit] = ln;
    }
}

// Hebbian: same staged structure over lat_mean; block partial sums
__global__ __launch_bounds__(256) void hebb_kernel(
    const float* __restrict__ lw, const float* __restrict__ lm,
    const float* __restrict__ lri_d, const float* __restrict__ wsum_ws,
    float* __restrict__ partials)
{
    __shared__ float win[2548];
    __shared__ float lriS[2404];
    __shared__ float wred[4];
    const int tid = threadIdx.x;
    const int wave = tid >> 6, lane = tid & 63;
    const int unit0 = blockIdx.x * 4;
    const int r0 = unit0 >> 7, c0 = unit0 & 127;

    for (int i = tid; i < 2404; i += 256) lriS[i] = lri_d[i];
    for (int i = tid; i < 2548; i += 256) {
        int wy = i / 52, wx = i - wy * 52;
        int rr = r0 - 24 + wy, cc = c0 - 24 + wx;
        float v = 0.0f;
        if (rr >= 0 && rr < 128 && cc >= 0 && cc < 128) v = lm[rr * 128 + cc];
        win[(i & 3) * 637 + (i >> 2)] = v;
    }
    __syncthreads();

    const int unit = unit0 + wave;
    const int base = unit * KL;
    const int h = (-base) & 3;
    const int tl = (base + KL) & 3;
    const int m4 = (KL - h - tl) >> 2;
    const int rem = m4 - 576;

    const v4f* w4p = (const v4f*)(lw + base + h);
    v4f wv[9];
    #pragma unroll
    for (int i = 0; i < 9; i++) wv[i] = w4p[lane + (i << 6)];
    v4f wv9 = (v4f)(0.0f);
    bool has9 = lane < rem;
    if (has9) wv9 = w4p[576 + lane];
    float whd = 0.0f, wtl = 0.0f;
    if (lane < h)  whd = lw[base + lane];
    if (lane < tl) wtl = lw[base + KL - tl + lane];

    float dot = 0.0f;
    if (lane < h) {
        int rr = lane + wave;
        dot = fmaf(whd * lriS[(lane & 3) * 601 + (lane >> 2)],
                   win[(rr & 3) * 637 + (rr >> 2)], dot);
    }
    if (lane < tl) {
        int k = KL - tl + lane;
        int ky = (int)(((unsigned)k * 42800u) >> 21);
        int rr = k + 3 * ky + wave;
        dot = fmaf(wtl * lriS[(k & 3) * 601 + (k >> 2)],
                   win[(rr & 3) * 637 + (rr >> 2)], dot);
    }
    #pragma unroll
    for (int i = 0; i < 9; i++) {
        int kq = h + ((lane + (i << 6)) << 2);
        #pragma unroll
        for (int e = 0; e < 4; e++) {
            int k = kq + e;
            float w = wv[i][e];
            int ky = (int)(((unsigned)k * 42800u) >> 21);
            int rr = k + 3 * ky + wave;
            dot = fmaf(w * lriS[(k & 3) * 601 + (k >> 2)],
                       win[(rr & 3) * 637 + (rr >> 2)], dot);
        }
    }
    if (has9) {
        int kq = h + ((576 + lane) << 2);
        #pragma unroll
        for (int e = 0; e < 4; e++) {
            int k = kq + e;
            float w = wv9[e];
            int ky = (int)(((unsigned)k * 42800u) >> 21);
            int rr = k + 3 * ky + wave;
            dot = fmaf(w * lriS[(k & 3) * 601 + (k >> 2)],
                       win[(rr & 3) * 637 + (rr >> 2)], dot);
        }
    }
    for (int off = 32; off > 0; off >>= 1) dot += __shfl_down(dot, off);
    if (lane == 0) {
        int rc = 24 * 52 + 24 + wave;
        float center = win[(rc & 3) * 637 + (rc >> 2)];
        wred[wave] = center * (240.1f / wsum_ws[unit]) * dot;
    }
    __syncthreads();
    if (tid == 0) partials[blockIdx.x] = wred[0] + wred[1] + wred[2] + wred[3];
}

__global__ __launch_bounds__(256) void reduce_kernel(
    const float* __restrict__ partials, float* __restrict__ out)
{
    __shared__ float red[256];
    float s = 0.0f;
    for (int i = threadIdx.x; i < 4096; i += 256) s += partials[i];
    red[threadIdx.x] = s;
    __syncthreads();
    for (int off = 128; off > 0; off >>= 1) {
        if (threadIdx.x < off) red[threadIdx.x] += red[threadIdx.x + off];
        __syncthreads();
    }
    if (threadIdx.x == 0) out[0] = red[0];
}

extern "C" void kernel_launch(void* const* d_in, const int* in_sizes, int n_in,
                              void* d_out, int out_size, void* d_ws, size_t ws_size,
                              hipStream_t stream) {
    const float* x        = (const float*)d_in[0];
    const float* rfs      = (const float*)d_in[1];
    const float* lw       = (const float*)d_in[2];
    const float* ada      = (const float*)d_in[3];
    const float* last_lat = (const float*)d_in[4];
    const float* lm0      = (const float*)d_in[5];
    float* out = (float*)d_out;
    float* ws  = (float*)d_ws;

    init_consts<<<1, 256, 0, stream>>>(ws);
    aff_kernel<<<L / 4, 256, 0, stream>>>(x, rfs, ada, ws + WS_AENVD,
                                          out, out + OUT_XT, ws + WS_AFF);
    for (int it = 0; it < 10; ++it) {
        const float* lat_in = (it == 0) ? last_lat : (ws + WS_LAT);
        const float* lmsrc  = (it == 0) ? lm0 : (ws + WS_LM);
        smooth_kernel<<<L / 256, 256, 0, stream>>>(lat_in, ws + WS_SRE, ws + WS_LATS);
        lat_kernel<<<L / 4, 256, 0, stream>>>(lw, ws + WS_LATS, ws + WS_AFF,
                                              ws + WS_LRID, ws + WS_WSUM,
                                              lmsrc, ws + WS_LM, ws + WS_LAT,
                                              (it == 9) ? (out + OUT_LAT) : nullptr,
                                              (it == 0) ? 1 : 0);
    }
    hebb_kernel<<<L / 4, 256, 0, stream>>>(lw, ws + WS_LM, ws + WS_LRID,
                                           ws + WS_WSUM, ws + WS_PART);
    reduce_kernel<<<1, 256, 0, stream>>>(ws + WS_PART, out + OUT_CORR);
}

// Round 5
// 557.783 us; speedup vs baseline: 1.2585x; 1.1441x over previous
//
#include <hip/hip_runtime.h>
#include <math.h>

#define S 128
#define L (S*S)            // 16384
#define AK 25
#define KA 625
#define LK 49
#define KL 2401
#define XW 152
#define PI2 1.57079632679489662f
#define MSCALE 1024.0f

typedef float v4f __attribute__((ext_vector_type(4)));
typedef _Float16 v4h __attribute__((ext_vector_type(4)));

// ws layout (float offsets)
#define WS_AENVD   0        // deinterleaved aff env, 628 floats
#define WS_SRE     1024
#define WS_LRIRAW  2048
#define WS_LRID    5120     // deinterleaved lri, 2404 floats
#define WS_AFF     8192
#define WS_LAT     40960
#define WS_LATS    57344
#define WS_LM      73728
#define WS_PART    90112
#define WS_M16     102400   // fp16 premultiplied weights, 16384*2401 halves (78.7 MB)

// out layout (float offsets): raw_aff[16384], lat[16384], corr[1], x_tiles[10240000]
#define OUT_LAT   16384
#define OUT_CORR  32768
#define OUT_XT    32769

__global__ __launch_bounds__(256) void init_consts(float* __restrict__ ws) {
    const int t = threadIdx.x;
    float* aenvd  = ws + WS_AENVD;
    float* sre    = ws + WS_SRE;
    float* lrraw  = ws + WS_LRIRAW;
    float* lrid   = ws + WS_LRID;
    __shared__ float red[256];

    for (int k = t; k < KA; k += 256) {
        int ky = k / AK, kx = k - ky * AK;
        float dy = (float)ky - 12.0f, dx = (float)kx - 12.0f;
        float rd = sqrtf(dx*dx + dy*dy);
        float c  = cosf(fminf(rd * (1.0f/25.0f), 1.0f) * PI2);
        aenvd[(k & 3) * 157 + (k >> 2)] = c*c * (rd < 12.5f ? 1.0f : 0.0f);
    }

    float myv = 0.0f;
    if (t < 25) {
        int ky = t / 5, kx = t - ky * 5;
        float dy = (float)ky - 2.0f, dx = (float)kx - 2.0f;
        float rd = sqrtf(dx*dx + dy*dy);
        float c  = cosf(fminf(rd * 0.2f, 1.0f) * PI2);
        myv = c*c * (rd < 2.5f ? 1.0f : 0.0f);
    }
    red[t] = myv;
    __syncthreads();
    for (int off = 128; off > 0; off >>= 1) {
        if (t < off) red[t] += red[t + off];
        __syncthreads();
    }
    float ssum = red[0];
    __syncthreads();
    if (t < 25) sre[t] = myv / ssum;

    float localmax = 0.0f;
    for (int k = t; k < KL; k += 256) {
        int ky = k / LK, kx = k - ky * LK;
        float dy = (float)ky - 24.0f, dx = (float)kx - 24.0f;
        float rd = sqrtf(dx*dx + dy*dy);
        float ci = cosf(fminf(rd * 0.2f, 1.0f) * PI2);
        float im = ci*ci * (rd < 2.5f ? 1.0f : 0.0f);
        float co = cosf(fminf(rd * (1.0f/49.0f), 1.0f) * PI2);
        float le = co*co * (rd < 24.5f ? 1.0f : 0.0f) * (1.0f - im);
        lrraw[k] = le;
        localmax = fmaxf(localmax, le);
    }
    red[t] = localmax;
    __syncthreads();
    for (int off = 128; off > 0; off >>= 1) {
        if (t < off) red[t] = fmaxf(red[t], red[t + off]);
        __syncthreads();
    }
    float invm = 1.0f / red[0];
    __syncthreads();
    for (int k = t; k < KL; k += 256)
        lrid[(k & 3) * 601 + (k >> 2)] = lrraw[k] * invm;
}

// Precompute M16[l,k] = fp16( lw[l,k] * lri[k] * MSCALE / wsum[l] ).
// Wave per unit; full fp32 row staged in registers; one pass.
__global__ __launch_bounds__(256) void prep_kernel(
    const float* __restrict__ lw, const float* __restrict__ lri_d,
    _Float16* __restrict__ m16)
{
    __shared__ float lriS[2404];
    const int tid = threadIdx.x;
    const int wave = tid >> 6, lane = tid & 63;
    for (int i = tid; i < 2404; i += 256) lriS[i] = lri_d[i];
    __syncthreads();

    const int unit = blockIdx.x * 4 + wave;
    const int base = unit * KL;
    const int h = (-base) & 3;
    const int tl = (base + KL) & 3;
    const int m4 = (KL - h - tl) >> 2;
    const int rem = m4 - 576;

    const v4f* w4p = (const v4f*)(lw + base + h);
    v4f wv[9];
    #pragma unroll
    for (int i = 0; i < 9; i++) wv[i] = w4p[lane + (i << 6)];
    v4f wv9 = (v4f)(0.0f);
    bool has9 = lane < rem;
    if (has9) wv9 = w4p[576 + lane];
    float whd = 0.0f, wtl = 0.0f;
    if (lane < h)  whd = lw[base + lane];
    if (lane < tl) wtl = lw[base + KL - tl + lane];

    float wsum = whd + wtl;
    #pragma unroll
    for (int i = 0; i < 9; i++) wsum += wv[i][0] + wv[i][1] + wv[i][2] + wv[i][3];
    wsum += wv9[0] + wv9[1] + wv9[2] + wv9[3];
    #pragma unroll
    for (int off = 1; off < 64; off <<= 1) wsum += __shfl_xor(wsum, off);
    const float scale = MSCALE / wsum;

    v4h* m4p = (v4h*)(m16 + base + h);   // (base+h)%4==0 -> 8B aligned
    if (lane < h)
        m16[base + lane] = (_Float16)(whd * lriS[(lane & 3) * 601 + (lane >> 2)] * scale);
    if (lane < tl) {
        int k = KL - tl + lane;
        m16[base + k] = (_Float16)(wtl * lriS[(k & 3) * 601 + (k >> 2)] * scale);
    }
    #pragma unroll
    for (int i = 0; i < 9; i++) {
        int q = lane + (i << 6);
        int kq = h + (q << 2);
        v4h st;
        #pragma unroll
        for (int e = 0; e < 4; e++) {
            int k = kq + e;
            st[e] = (_Float16)(wv[i][e] * lriS[(k & 3) * 601 + (k >> 2)] * scale);
        }
        m4p[q] = st;
    }
    if (has9) {
        int q = 576 + lane;
        int kq = h + (q << 2);
        v4h st;
        #pragma unroll
        for (int e = 0; e < 4; e++) {
            int k = kq + e;
            st[e] = (_Float16)(wv9[e] * lriS[(k & 3) * 601 + (k >> 2)] * scale);
        }
        m4p[q] = st;
    }
}

// Afferent: wave per unit; staged register loads; LDS x-window + env; v4f nt stores
__global__ __launch_bounds__(256) void aff_kernel(
    const float* __restrict__ x, const float* __restrict__ rfs,
    const float* __restrict__ ada, const float* __restrict__ aenv_d,
    float* __restrict__ raw_aff_out, float* __restrict__ xtiles_out,
    float* __restrict__ aff_ws)
{
    __shared__ float xwin[700];
    __shared__ float env[628];
    const int tid = threadIdx.x;
    const int wave = tid >> 6, lane = tid & 63;
    const int unit0 = blockIdx.x * 4;
    const int r0 = unit0 >> 7, c0 = unit0 & 127;

    for (int i = tid; i < 628; i += 256) env[i] = aenv_d[i];
    for (int i = tid; i < 700; i += 256) {
        int wy = i / 28, wx = i - wy * 28;
        xwin[(i & 3) * 175 + (i >> 2)] = x[(r0 + wy) * XW + c0 + wx];
    }
    __syncthreads();

    const int unit = unit0 + wave;
    const int base = unit * KA;
    const int h = (-base) & 3;
    const int tl = (base + KA) & 3;
    const int m4 = (KA - h - tl) >> 2;
    const int rem = m4 - 128;

    const v4f* w4p = (const v4f*)(rfs + base + h);
    v4f wv0 = w4p[lane];
    v4f wv1 = w4p[lane + 64];
    v4f wv2 = (v4f)(0.0f);
    bool has2 = lane < rem;
    if (has2) wv2 = w4p[128 + lane];
    float wh = 0.0f, wt = 0.0f;
    if (lane < h)  wh = rfs[base + lane];
    if (lane < tl) wt = rfs[base + KA - tl + lane];

    float* trow = xtiles_out + (size_t)unit * KA;
    v4f* t4p = (v4f*)(trow + h);
    float adot = 0.0f, rsum = 0.0f;

    if (lane < h) {
        int j = lane + wave;
        float xt = xwin[(j & 3) * 175 + (j >> 2)] * env[(lane & 3) * 157 + (lane >> 2)];
        trow[lane] = xt;
        adot = fmaf(xt, wh, adot); rsum += wh;
    }
    if (lane < tl) {
        int k = KA - tl + lane;
        int ky = (int)(((unsigned)k * 83887u) >> 21);
        int j = k + 3 * ky + wave;
        float xt = xwin[(j & 3) * 175 + (j >> 2)] * env[(k & 3) * 157 + (k >> 2)];
        trow[k] = xt;
        adot = fmaf(xt, wt, adot); rsum += wt;
    }
    #pragma unroll
    for (int i = 0; i < 2; i++) {
        v4f wq = (i == 0) ? wv0 : wv1;
        int q = lane + (i << 6);
        int kq = h + (q << 2);
        v4f st;
        #pragma unroll
        for (int e = 0; e < 4; e++) {
            int k = kq + e;
            int ky = (int)(((unsigned)k * 83887u) >> 21);
            int j = k + 3 * ky + wave;
            float xt = xwin[(j & 3) * 175 + (j >> 2)] * env[(k & 3) * 157 + (k >> 2)];
            st[e] = xt;
            adot = fmaf(xt, wq[e], adot);
            rsum += wq[e];
        }
        __builtin_nontemporal_store(st, &t4p[q]);
    }
    if (has2) {
        int q = 128 + lane;
        int kq = h + (q << 2);
        v4f st;
        #pragma unroll
        for (int e = 0; e < 4; e++) {
            int k = kq + e;
            int ky = (int)(((unsigned)k * 83887u) >> 21);
            int j = k + 3 * ky + wave;
            float xt = xwin[(j & 3) * 175 + (j >> 2)] * env[(k & 3) * 157 + (k >> 2)];
            st[e] = xt;
            adot = fmaf(xt, wv2[e], adot);
            rsum += wv2[e];
        }
        __builtin_nontemporal_store(st, &t4p[q]);
    }

    for (int off = 32; off > 0; off >>= 1) {
        adot += __shfl_down(adot, off);
        rsum += __shfl_down(rsum, off);
    }
    if (lane == 0) {
        float inv = 1.0f / rsum;
        raw_aff_out[unit] = 62.5f * adot * inv;
        aff_ws[unit] = adot * inv - ada[unit];
    }
}

// 5x5 reflect-pad smoothing conv
__global__ __launch_bounds__(256) void smooth_kernel(
    const float* __restrict__ lat, const float* __restrict__ sre,
    float* __restrict__ lat_s)
{
    const int idx = blockIdx.x * 256 + threadIdx.x;
    const int r = idx >> 7, c = idx & 127;
    float acc = 0.0f;
    #pragma unroll
    for (int a = 0; a < 5; a++) {
        int rr = r + a - 2;
        rr = rr < 0 ? -rr : (rr > 127 ? 254 - rr : rr);
        #pragma unroll
        for (int b = 0; b < 5; b++) {
            int cc = c + b - 2;
            cc = cc < 0 ? -cc : (cc > 127 ? 254 - cc : cc);
            acc = fmaf(sre[a * 5 + b], lat[rr * 128 + cc], acc);
        }
    }
    lat_s[idx] = acc;
}

// Lateral iteration with fp16 premultiplied weights. Wave per unit.
// dot = sum_k M16[k]*win[k]  (lri & 1/wsum folded in, scaled by MSCALE)
__global__ __launch_bounds__(256) void lat_kernel(
    const _Float16* __restrict__ m16, const float* __restrict__ lat_s,
    const float* __restrict__ aff, const float* __restrict__ lm_in,
    float* __restrict__ lm_out, float* __restrict__ lat_out,
    float* __restrict__ lat_final)
{
    __shared__ float win[2548];   // [(rr&3)*637 + (rr>>2)], rr = k + 3*ky + wave
    const int tid = threadIdx.x;
    const int wave = tid >> 6, lane = tid & 63;
    const int unit0 = blockIdx.x * 4;
    const int r0 = unit0 >> 7, c0 = unit0 & 127;

    for (int i = tid; i < 2548; i += 256) {
        int wy = i / 52, wx = i - wy * 52;
        int rr = r0 - 24 + wy, cc = c0 - 24 + wx;
        float v = 0.0f;
        if (rr >= 0 && rr < 128 && cc >= 0 && cc < 128) v = lat_s[rr * 128 + cc];
        win[(i & 3) * 637 + (i >> 2)] = v;
    }
    __syncthreads();

    const int unit = unit0 + wave;
    const int base = unit * KL;
    const int h = (-base) & 3;
    const int tl = (base + KL) & 3;
    const int m4 = (KL - h - tl) >> 2;
    const int rem = m4 - 576;

    const v4h* m4p = (const v4h*)(m16 + base + h);
    v4h wv[9];
    #pragma unroll
    for (int i = 0; i < 9; i++) wv[i] = m4p[lane + (i << 6)];
    v4h wv9 = (v4h)((_Float16)0.0f);
    bool has9 = lane < rem;
    if (has9) wv9 = m4p[576 + lane];
    float whd = 0.0f, wtl = 0.0f;
    if (lane < h)  whd = (float)m16[base + lane];
    if (lane < tl) wtl = (float)m16[base + KL - tl + lane];

    float dot = 0.0f;
    if (lane < h) {
        int rr = lane + wave;
        dot = fmaf(whd, win[(rr & 3) * 637 + (rr >> 2)], dot);
    }
    if (lane < tl) {
        int k = KL - tl + lane;
        int ky = (int)(((unsigned)k * 42800u) >> 21);
        int rr = k + 3 * ky + wave;
        dot = fmaf(wtl, win[(rr & 3) * 637 + (rr >> 2)], dot);
    }
    #pragma unroll
    for (int i = 0; i < 9; i++) {
        int kq = h + ((lane + (i << 6)) << 2);
        #pragma unroll
        for (int e = 0; e < 4; e++) {
            int k = kq + e;
            int ky = (int)(((unsigned)k * 42800u) >> 21);
            int rr = k + 3 * ky + wave;
            dot = fmaf((float)wv[i][e], win[(rr & 3) * 637 + (rr >> 2)], dot);
        }
    }
    if (has9) {
        int kq = h + ((576 + lane) << 2);
        #pragma unroll
        for (int e = 0; e < 4; e++) {
            int k = kq + e;
            int ky = (int)(((unsigned)k * 42800u) >> 21);
            int rr = k + 3 * ky + wave;
            dot = fmaf((float)wv9[e], win[(rr & 3) * 637 + (rr >> 2)], dot);
        }
    }

    for (int off = 32; off > 0; off >>= 1) dot += __shfl_down(dot, off);
    if (lane == 0) {
        int rc = 24 * 52 + 24 + wave;
        float ls = win[(rc & 3) * 637 + (rc >> 2)];
        float ln = fmaxf(ls + aff[unit] - (2.5f / MSCALE) * dot, 0.0f) * 2.2f;
        ln = tanhf(ln * 1.5f) * (1.0f / 1.5f);
        float lm = 0.5f * lm_in[unit] + 0.5f * ln;
        lm_out[unit] = lm;
        lat_out[unit] = ln;
        if (lat_final) lat_final[unit] = ln;
    }
}

// Hebbian using M16: corr_l = center * (240.1/MSCALE) * sum_k M16*win(lm)
__global__ __launch_bounds__(256) void hebb_kernel(
    const _Float16* __restrict__ m16, const float* __restrict__ lm,
    float* __restrict__ partials)
{
    __shared__ float win[2548];
    __shared__ float wred[4];
    const int tid = threadIdx.x;
    const int wave = tid >> 6, lane = tid & 63;
    const int unit0 = blockIdx.x * 4;
    const int r0 = unit0 >> 7, c0 = unit0 & 127;

    for (int i = tid; i < 2548; i += 256) {
        int wy = i / 52, wx = i - wy * 52;
        int rr = r0 - 24 + wy, cc = c0 - 24 + wx;
        float v = 0.0f;
        if (rr >= 0 && rr < 128 && cc >= 0 && cc < 128) v = lm[rr * 128 + cc];
        win[(i & 3) * 637 + (i >> 2)] = v;
    }
    __syncthreads();

    const int unit = unit0 + wave;
    const int base = unit * KL;
    const int h = (-base) & 3;
    const int tl = (base + KL) & 3;
    const int m4 = (KL - h - tl) >> 2;
    const int rem = m4 - 576;

    const v4h* m4p = (const v4h*)(m16 + base + h);
    v4h wv[9];
    #pragma unroll
    for (int i = 0; i < 9; i++) wv[i] = m4p[lane + (i << 6)];
    v4h wv9 = (v4h)((_Float16)0.0f);
    bool has9 = lane < rem;
    if (has9) wv9 = m4p[576 + lane];
    float whd = 0.0f, wtl = 0.0f;
    if (lane < h)  whd = (float)m16[base + lane];
    if (lane < tl) wtl = (float)m16[base + KL - tl + lane];

    float dot = 0.0f;
    if (lane < h) {
        int rr = lane + wave;
        dot = fmaf(whd, win[(rr & 3) * 637 + (rr >> 2)], dot);
    }
    if (lane < tl) {
        int k = KL - tl + lane;
        int ky = (int)(((unsigned)k * 42800u) >> 21);
        int rr = k + 3 * ky + wave;
        dot = fmaf(wtl, win[(rr & 3) * 637 + (rr >> 2)], dot);
    }
    #pragma unroll
    for (int i = 0; i < 9; i++) {
        int kq = h + ((lane + (i << 6)) << 2);
        #pragma unroll
        for (int e = 0; e < 4; e++) {
            int k = kq + e;
            int ky = (int)(((unsigned)k * 42800u) >> 21);
            int rr = k + 3 * ky + wave;
            dot = fmaf((float)wv[i][e], win[(rr & 3) * 637 + (rr >> 2)], dot);
        }
    }
    if (has9) {
        int kq = h + ((576 + lane) << 2);
        #pragma unroll
        for (int e = 0; e < 4; e++) {
            int k = kq + e;
            int ky = (int)(((unsigned)k * 42800u) >> 21);
            int rr = k + 3 * ky + wave;
            dot = fmaf((float)wv9[e], win[(rr & 3) * 637 + (rr >> 2)], dot);
        }
    }
    for (int off = 32; off > 0; off >>= 1) dot += __shfl_down(dot, off);
    if (lane == 0) {
        int rc = 24 * 52 + 24 + wave;
        float center = win[(rc & 3) * 637 + (rc >> 2)];
        wred[wave] = center * (240.1f / MSCALE) * dot;
    }
    __syncthreads();
    if (tid == 0) partials[blockIdx.x] = wred[0] + wred[1] + wred[2] + wred[3];
}

__global__ __launch_bounds__(256) void reduce_kernel(
    const float* __restrict__ partials, float* __restrict__ out)
{
    __shared__ float red[256];
    float s = 0.0f;
    for (int i = threadIdx.x; i < 4096; i += 256) s += partials[i];
    red[threadIdx.x] = s;
    __syncthreads();
    for (int off = 128; off > 0; off >>= 1) {
        if (threadIdx.x < off) red[threadIdx.x] += red[threadIdx.x + off];
        __syncthreads();
    }
    if (threadIdx.x == 0) out[0] = red[0];
}

extern "C" void kernel_launch(void* const* d_in, const int* in_sizes, int n_in,
                              void* d_out, int out_size, void* d_ws, size_t ws_size,
                              hipStream_t stream) {
    const float* x        = (const float*)d_in[0];
    const float* rfs      = (const float*)d_in[1];
    const float* lw       = (const float*)d_in[2];
    const float* ada      = (const float*)d_in[3];
    const float* last_lat = (const float*)d_in[4];
    const float* lm0      = (const float*)d_in[5];
    float* out = (float*)d_out;
    float* ws  = (float*)d_ws;
    _Float16* m16 = (_Float16*)(ws + WS_M16);

    init_consts<<<1, 256, 0, stream>>>(ws);
    aff_kernel<<<L / 4, 256, 0, stream>>>(x, rfs, ada, ws + WS_AENVD,
                                          out, out + OUT_XT, ws + WS_AFF);
    prep_kernel<<<L / 4, 256, 0, stream>>>(lw, ws + WS_LRID, m16);
    for (int it = 0; it < 10; ++it) {
        const float* lat_in = (it == 0) ? last_lat : (ws + WS_LAT);
        const float* lmsrc  = (it == 0) ? lm0 : (ws + WS_LM);
        smooth_kernel<<<L / 256, 256, 0, stream>>>(lat_in, ws + WS_SRE, ws + WS_LATS);
        lat_kernel<<<L / 4, 256, 0, stream>>>(m16, ws + WS_LATS, ws + WS_AFF,
                                              lmsrc, ws + WS_LM, ws + WS_LAT,
                                              (it == 9) ? (out + OUT_LAT) : nullptr);
    }
    hebb_kernel<<<L / 4, 256, 0, stream>>>(m16, ws + WS_LM, ws + WS_PART);
    reduce_kernel<<<1, 256, 0, stream>>>(ws + WS_PART, out + OUT_CORR);
}